// Round 1
// baseline (444.959 us; speedup 1.0000x reference)
//
#include <hip/hip_runtime.h>

// Problem constants (from reference setup_inputs)
constexpr int B = 2, C = 256, H = 200, W = 336;
constexpr int HW = H * W;
constexpr int OH = 14, OW = 14, OHW = OH * OW;   // 196 samples per ROI
constexpr float SCALE = 0.25f;

constexpr int CSPLIT = 4;            // channel slices per ROI
constexpr int CPB = C / CSPLIT;      // 64 channels per block

__global__ __launch_bounds__(256) void roi_align_kernel(
    const float* __restrict__ feat,   // (B, C, H, W)
    const float* __restrict__ rois,   // (R, 5)
    float* __restrict__ out)          // (R, C, OH, OW)
{
    const int r   = blockIdx.x;
    const int c0  = blockIdx.y * CPB;
    const int tid = threadIdx.x;

    // ROI params (block-uniform values loaded per-lane; b forced scalar)
    const float* roi = rois + r * 5;
    const float bf = roi[0];
    const float x1 = roi[1], y1 = roi[2], x2 = roi[3], y2 = roi[4];
    const int b = __builtin_amdgcn_readfirstlane((int)bf);

    const int s = tid;
    if (s >= OHW) return;            // lanes 196..255 idle (wave 3 keeps 4 lanes)

    const int oh = s / OW;
    const int ow = s - oh * OW;

    // Sample position in feature space (matches reference exactly)
    const float fx = (x1 + (ow + 0.5f) * (1.0f / OW) * (x2 - x1)) * SCALE - 0.5f;
    const float fy = (y1 + (oh + 0.5f) * (1.0f / OH) * (y2 - y1)) * SCALE - 0.5f;

    const float x0f = floorf(fx), y0f = floorf(fy);
    const float lx = fx - x0f,   ly = fy - y0f;
    const int x0 = (int)x0f, y0 = (int)y0f;
    const int x1i = x0 + 1,  y1i = y0 + 1;

    // Per-corner validity folded into weights (reference: v * valid)
    const float vx0 = (x0  >= 0 && x0  < W) ? 1.0f : 0.0f;
    const float vx1 = (x1i >= 0 && x1i < W) ? 1.0f : 0.0f;
    const float vy0 = (y0  >= 0 && y0  < H) ? 1.0f : 0.0f;
    const float vy1 = (y1i >= 0 && y1i < H) ? 1.0f : 0.0f;

    const float w00 = (1.0f - ly) * (1.0f - lx) * vy0 * vx0;
    const float w01 = (1.0f - ly) * lx          * vy0 * vx1;
    const float w10 = ly          * (1.0f - lx) * vy1 * vx0;
    const float w11 = ly          * lx          * vy1 * vx1;

    // Clamped flat offsets within one channel plane
    const int cx0 = min(max(x0, 0),  W - 1), cx1 = min(max(x1i, 0), W - 1);
    const int cy0 = min(max(y0, 0),  H - 1), cy1 = min(max(y1i, 0), H - 1);
    const int i00 = cy0 * W + cx0, i01 = cy0 * W + cx1;
    const int i10 = cy1 * W + cx0, i11 = cy1 * W + cx1;

    // Scalar-base pointers: b, c0 block-uniform; per-lane offsets i00..i11, s
    const float* p  = feat + (size_t)(b * C + c0) * HW;
    float*       op = out  + (size_t)r * C * OHW + (size_t)c0 * OHW + s;

    #pragma unroll 4
    for (int c = 0; c < CPB; ++c) {
        const float v00 = p[i00], v01 = p[i01], v10 = p[i10], v11 = p[i11];
        *op = fmaf(w00, v00, fmaf(w01, v01, fmaf(w10, v10, w11 * v11)));
        p  += HW;
        op += OHW;
    }
}

extern "C" void kernel_launch(void* const* d_in, const int* in_sizes, int n_in,
                              void* d_out, int out_size, void* d_ws, size_t ws_size,
                              hipStream_t stream) {
    const float* feat = (const float*)d_in[0];
    const float* rois = (const float*)d_in[1];
    float* out = (float*)d_out;

    const int R = in_sizes[1] / 5;   // 1000
    dim3 grid(R, CSPLIT);
    dim3 block(256);
    roi_align_kernel<<<grid, block, 0, stream>>>(feat, rois, out);
}

// Round 2
// 437.536 us; speedup vs baseline: 1.0170x; 1.0170x over previous
//
#include <hip/hip_runtime.h>

// Problem constants (from reference setup_inputs)
constexpr int B = 2, C = 256, H = 200, W = 336;
constexpr int HW = H * W;
constexpr int OH = 14, OW = 14, OHW = OH * OW;   // 196 samples per ROI
constexpr float SCALE = 0.25f;

constexpr int CSPLIT = 4;            // channel slices per ROI
constexpr int CPB = C / CSPLIT;      // 64 channels per block

// 8-byte pair load with only 4-byte alignment guarantee.
typedef float f2 __attribute__((ext_vector_type(2), aligned(4)));

__global__ __launch_bounds__(256) void roi_align_kernel(
    const float* __restrict__ feat,   // (B, C, H, W)
    const float* __restrict__ rois,   // (R, 5)
    float* __restrict__ out)          // (R, C, OH, OW)
{
    const int r   = blockIdx.x;
    const int c0  = blockIdx.y * CPB;
    const int tid = threadIdx.x;

    const float* roi = rois + r * 5;
    const float bf = roi[0];
    const float x1 = roi[1], y1 = roi[2], x2 = roi[3], y2 = roi[4];
    const int b = __builtin_amdgcn_readfirstlane((int)bf);

    const int s = tid;
    if (s >= OHW) return;            // lanes 196..255 idle

    const int oh = s / OW;
    const int ow = s - oh * OW;

    // Sample position in feature space (matches reference exactly)
    const float fx = (x1 + (ow + 0.5f) * (1.0f / OW) * (x2 - x1)) * SCALE - 0.5f;
    const float fy = (y1 + (oh + 0.5f) * (1.0f / OH) * (y2 - y1)) * SCALE - 0.5f;

    const float x0f = floorf(fx), y0f = floorf(fy);
    const float lx = fx - x0f,   ly = fy - y0f;
    const int x0 = (int)x0f,  y0 = (int)y0f;
    const int x1i = x0 + 1,   y1i = y0 + 1;

    // Validity folded into weights (reference: v * valid)
    const float cxw0 = ((x0  >= 0 && x0  < W) ? 1.0f : 0.0f) * (1.0f - lx);
    const float cxw1 = ((x1i >= 0 && x1i < W) ? 1.0f : 0.0f) * lx;
    const float ryw0 = ((y0  >= 0 && y0  < H) ? 1.0f : 0.0f) * (1.0f - ly);
    const float ryw1 = ((y1i >= 0 && y1i < H) ? 1.0f : 0.0f) * ly;

    // Pair base clamped so [px, px+1] is always in-row; if clamped, the
    // useful corner moved to the other slot -> pre-swap pair weights.
    // (The invalid corner's weight is already 0, so the swap is lossless.)
    const int px = min(max(x0, 0), W - 2);
    const bool swp = (x0 != px);
    const float wxa = swp ? cxw1 : cxw0;   // weight on pair.x
    const float wxb = swp ? cxw0 : cxw1;   // weight on pair.y
    const float a0 = ryw0 * wxa, b0 = ryw0 * wxb;   // row y0 pair weights
    const float a1 = ryw1 * wxa, b1 = ryw1 * wxb;   // row y0+1 pair weights

    const int cy0 = min(max(y0,  0), H - 1);
    const int cy1 = min(max(y1i, 0), H - 1);
    const int i0 = cy0 * W + px;   // row-0 pair offset within a channel plane
    const int i1 = cy1 * W + px;   // row-1 pair offset

    const float* p  = feat + (size_t)(b * C + c0) * HW;
    float*       op = out  + (size_t)r * C * OHW + (size_t)c0 * OHW + s;

    #pragma unroll 8
    for (int c = 0; c < CPB; ++c) {
        const f2 r0 = *reinterpret_cast<const f2*>(p + i0);  // v00, v01
        const f2 r1 = *reinterpret_cast<const f2*>(p + i1);  // v10, v11
        *op = fmaf(a0, r0.x, fmaf(b0, r0.y, fmaf(a1, r1.x, b1 * r1.y)));
        p  += HW;
        op += OHW;
    }
}

extern "C" void kernel_launch(void* const* d_in, const int* in_sizes, int n_in,
                              void* d_out, int out_size, void* d_ws, size_t ws_size,
                              hipStream_t stream) {
    const float* feat = (const float*)d_in[0];
    const float* rois = (const float*)d_in[1];
    float* out = (float*)d_out;

    const int R = in_sizes[1] / 5;   // 1000
    dim3 grid(R, CSPLIT);
    dim3 block(256);
    roi_align_kernel<<<grid, block, 0, stream>>>(feat, rois, out);
}

// Round 3
// 412.967 us; speedup vs baseline: 1.0775x; 1.0595x over previous
//
#include <hip/hip_runtime.h>

// Problem constants (from reference setup_inputs)
constexpr int B = 2, C = 256, H = 200, W = 336;
constexpr int HW = H * W;
constexpr int OH = 14, OW = 14, OHW = OH * OW;   // 196 samples per ROI
constexpr float SCALE = 0.25f;
constexpr int R = 1000;

constexpr int CSPLIT = 4;            // channel slices per ROI
constexpr int CPB = C / CSPLIT;      // 64 channels per block
constexpr int NXCD = 8;
constexpr int RPX = R / NXCD;        // 125 ROIs per XCD

// 8-byte pair load with only 4-byte alignment guarantee.
typedef float f2 __attribute__((ext_vector_type(2), aligned(4)));

// ---------------------------------------------------------------------------
// Kernel A: sort ROI indices by (batch, 64px y-band, x-center) so that
// spatially adjacent ROIs get adjacent ranks. One block, bitonic over 1024.
// ---------------------------------------------------------------------------
__global__ __launch_bounds__(1024) void sort_rois_kernel(
    const float* __restrict__ rois, int* __restrict__ order)
{
    __shared__ unsigned key[1024];
    const int t = threadIdx.x;

    unsigned k = 0xFFFFFFFFu;
    if (t < R) {
        const float* roi = rois + t * 5;
        const int   b  = (int)roi[0];
        const float cx = 0.5f * (roi[1] + roi[3]);
        const float cy = 0.5f * (roi[2] + roi[4]);
        const int yb   = min(12, max(0, (int)cy >> 6));   // 64-px y bands
        const int band = (b << 4) | yb;                    // 0..28
        const int cxi  = min(2047, max(0, (int)cx));       // 0..1343
        k = ((unsigned)band << 21) | ((unsigned)cxi << 10) | (unsigned)t;
    }
    key[t] = k;

    // Bitonic sort, ascending; thread with smaller index does the swap.
    for (int size = 2; size <= 1024; size <<= 1) {
        for (int stride = size >> 1; stride > 0; stride >>= 1) {
            __syncthreads();
            const int j = t ^ stride;
            if (j > t) {
                const bool up = ((t & size) == 0);
                const unsigned a = key[t], b2 = key[j];
                if ((a > b2) == up) { key[t] = b2; key[j] = a; }
            }
        }
    }
    __syncthreads();
    if (t < R) order[t] = (int)(key[t] & 1023u);
}

// ---------------------------------------------------------------------------
// Kernel B: ROI-Align. blockIdx%8 pins a spatial ROI chunk to one XCD so the
// per-XCD 4MB L2 sees cross-ROI line reuse (attacks 5x fetch redundancy).
// ---------------------------------------------------------------------------
__global__ __launch_bounds__(256) void roi_align_kernel(
    const float* __restrict__ feat,   // (B, C, H, W)
    const float* __restrict__ rois,   // (R, 5)
    const int*  __restrict__ order,   // (R) spatially sorted ROI indices
    float* __restrict__ out)          // (R, C, OH, OW)
{
    const int bid   = blockIdx.x;
    const int xcd   = bid & (NXCD - 1);       // dispatch round-robins XCDs
    const int slot  = bid >> 3;               // 0..(RPX*CSPLIT-1)
    const int slice = slot & (CSPLIT - 1);    // slice inner: all 4 slices of
    const int rank  = slot >> 2;              // adjacent ROIs co-resident
    const int r     = order[xcd * RPX + rank];
    const int c0    = slice * CPB;
    const int tid   = threadIdx.x;

    const float* roi = rois + r * 5;
    const float bf = roi[0];
    const float x1 = roi[1], y1 = roi[2], x2 = roi[3], y2 = roi[4];
    const int b = __builtin_amdgcn_readfirstlane((int)bf);

    const int s = tid;
    if (s >= OHW) return;            // lanes 196..255 idle

    const int oh = s / OW;
    const int ow = s - oh * OW;

    // Sample position in feature space (matches reference exactly)
    const float fx = (x1 + (ow + 0.5f) * (1.0f / OW) * (x2 - x1)) * SCALE - 0.5f;
    const float fy = (y1 + (oh + 0.5f) * (1.0f / OH) * (y2 - y1)) * SCALE - 0.5f;

    const float x0f = floorf(fx), y0f = floorf(fy);
    const float lx = fx - x0f,   ly = fy - y0f;
    const int x0 = (int)x0f,  y0 = (int)y0f;
    const int x1i = x0 + 1,   y1i = y0 + 1;

    // Validity folded into weights (reference: v * valid)
    const float cxw0 = ((x0  >= 0 && x0  < W) ? 1.0f : 0.0f) * (1.0f - lx);
    const float cxw1 = ((x1i >= 0 && x1i < W) ? 1.0f : 0.0f) * lx;
    const float ryw0 = ((y0  >= 0 && y0  < H) ? 1.0f : 0.0f) * (1.0f - ly);
    const float ryw1 = ((y1i >= 0 && y1i < H) ? 1.0f : 0.0f) * ly;

    // Pair base clamped so [px, px+1] stays in-row; pre-swap weights if
    // clamped (invalid corner's weight is already 0, so swap is lossless).
    const int px = min(max(x0, 0), W - 2);
    const bool swp = (x0 != px);
    const float wxa = swp ? cxw1 : cxw0;
    const float wxb = swp ? cxw0 : cxw1;
    const float a0 = ryw0 * wxa, b0 = ryw0 * wxb;
    const float a1 = ryw1 * wxa, b1 = ryw1 * wxb;

    const int cy0 = min(max(y0,  0), H - 1);
    const int cy1 = min(max(y1i, 0), H - 1);
    const int i0 = cy0 * W + px;
    const int i1 = cy1 * W + px;

    const float* p  = feat + (size_t)(b * C + c0) * HW;
    float*       op = out  + (size_t)r * C * OHW + (size_t)c0 * OHW + s;

    #pragma unroll 8
    for (int c = 0; c < CPB; ++c) {
        const f2 r0 = *reinterpret_cast<const f2*>(p + i0);  // v00, v01
        const f2 r1 = *reinterpret_cast<const f2*>(p + i1);  // v10, v11
        *op = fmaf(a0, r0.x, fmaf(b0, r0.y, fmaf(a1, r1.x, b1 * r1.y)));
        p  += HW;
        op += OHW;
    }
}

extern "C" void kernel_launch(void* const* d_in, const int* in_sizes, int n_in,
                              void* d_out, int out_size, void* d_ws, size_t ws_size,
                              hipStream_t stream) {
    const float* feat = (const float*)d_in[0];
    const float* rois = (const float*)d_in[1];
    float* out = (float*)d_out;
    int* order = (int*)d_ws;         // R ints of scratch

    sort_rois_kernel<<<1, 1024, 0, stream>>>(rois, order);

    dim3 grid(R * CSPLIT);
    dim3 block(256);
    roi_align_kernel<<<grid, block, 0, stream>>>(feat, rois, order, out);
}